// Round 6
// baseline (373.384 us; speedup 1.0000x reference)
//
#include <hip/hip_runtime.h>
#include <hip/hip_bf16.h>

typedef unsigned short u16;
typedef unsigned int u32;
typedef __attribute__((ext_vector_type(8))) short s8v;    // 8 bf16 (4 VGPRs) — MFMA A/B frag
typedef __attribute__((ext_vector_type(4))) float f4v;    // MFMA C/D frag
typedef __attribute__((ext_vector_type(4))) unsigned short u16x4;

#define MFMA16(a,b,c) __builtin_amdgcn_mfma_f32_16x16x32_bf16((a),(b),(c),0,0,0)

#define TOKENS 8192        // 4 * 2048
#define SEQ    2048
#define NH     16
#define DH     64
#define DIMK   1024
// fold 1/sqrt(64) * log2(e) into Q so P = exp2(S) directly
#define QPRE   0.18033688f

#if defined(__has_builtin)
#if __has_builtin(__builtin_amdgcn_exp2f)
#define EXP2(x) __builtin_amdgcn_exp2f(x)
#else
#define EXP2(x) __expf((x) * 0.69314718f)
#endif
#else
#define EXP2(x) __expf((x) * 0.69314718f)
#endif

// ---- bf16 helpers (round-to-nearest-even) ----
__device__ __forceinline__ u16 f2bf(float x){
  union { float f; u32 u; } v; v.f = x;
  u32 r = v.u + 0x7FFFu + ((v.u >> 16) & 1u);
  return (u16)(r >> 16);
}

// async global->LDS, 16B per lane; LDS dest = wave-uniform base + lane*16
__device__ __forceinline__ void gld16(const u16* g, u16* s){
  __builtin_amdgcn_global_load_lds(
      (const __attribute__((address_space(1))) unsigned int*)(const void*)g,
      (__attribute__((address_space(3))) unsigned int*)(void*)s,
      16, 0, 0);
}

// ---- cast fp32 -> bf16 (x) ----
__global__ __launch_bounds__(256) void k_cast(const float* __restrict__ src,
                                              u16* __restrict__ dst){
  int i = (blockIdx.x * 256 + threadIdx.x) * 4;
  float4 v = *(const float4*)(src + i);
  u16x4 vh;
  float a[4] = {v.x, v.y, v.z, v.w};
#pragma unroll
  for (int j = 0; j < 4; j++) vh[j] = f2bf(a[j]);
  *(u16x4*)(dst + i) = vh;
}

// ---- transpose weights to n-major bf16: out[n][k] = src[k][n] ----
__global__ __launch_bounds__(256) void k_transpose(const float* __restrict__ s0, int c0,
                                                   const float* __restrict__ s1, int c1,
                                                   int K, u16* __restrict__ dh){
  __shared__ float tile[64][65];
  int nb = blockIdx.x * 64, kb = blockIdx.y * 64;
  int tr = threadIdx.x >> 6, tc = threadIdx.x & 63;
#pragma unroll
  for (int i = 0; i < 16; i++){
    int k = kb + tr + i * 4, n = nb + tc;
    float v = (n < c0) ? s0[(size_t)k * c0 + n] : s1[(size_t)k * c1 + (n - c0)];
    tile[tr + i * 4][tc] = v;
  }
  __syncthreads();
#pragma unroll
  for (int i = 0; i < 16; i++){
    int nl = tr + i * 4, kl = tc;
    dh[(size_t)(nb + nl) * K + (kb + kl)] = f2bf(tile[kl][nl]);
  }
}

// ---- bf16 GEMM: C[8192 x N] = A[8192,1024] @ B^T-stored[N,1024], K=1024 ----
// A: double-buffered LDS (gld16 DMA), ONE barrier per BK=64 iter; prefetch of
// kc+1 is issued before compute(kc) so the barrier's vmcnt(0) drain is covered.
// B: direct-to-register s8v fragment loads (L2-resident under XCD swizzle) —
// no barrier dependency, overlaps MFMA.
// mpart=0: XCD owns nx/8 n-tiles, sweeps m (QKV: B-band L2-resident).
// mpart=1: XCD owns m-band, sweeps n (out-proj: A-band L2-resident).
// mode 0: epilogue routes cols: Q (prescaled) / K token-major, V^T+sigma.
// mode 1: epilogue adds bias, writes fp32 to Cf.
__global__ __launch_bounds__(256) void k_gemm(
    const u16* __restrict__ A, const u16* __restrict__ B, int nx, int mpart,
    int mode, const float* __restrict__ bias, float* __restrict__ Cf,
    u16* __restrict__ Qh, u16* __restrict__ Kh, u16* __restrict__ Vth)
{
  __shared__ u16 sA[2][2][128*32];   // [dbuf][cc][row*32] — 32 KB
  const int tid = threadIdx.x, wave = tid >> 6, lane = tid & 63;
  const int lm = lane & 15, quad = lane >> 4;

  // XCD-aware tile assignment
  const int bid = blockIdx.x;
  const int xcd = bid & 7, slot = bid >> 3;
  int xt, yt;
  if (mpart == 0){
    const int gpx = nx >> 3;
    xt = xcd * gpx + slot % gpx;
    yt = slot / gpx;
  } else {
    const int mg = (int)(gridDim.x >> 3) / nx;   // m-tiles per XCD
    xt = slot % nx;
    yt = xcd * mg + slot / nx;
  }
  const int m0 = yt * 128, n0 = xt * 128;

  const int cof = (lane & 3) * 8;
  const int rsub = lane >> 2;

  f4v acc[4][4];
#pragma unroll
  for (int i = 0; i < 4; i++)
#pragma unroll
    for (int j = 0; j < 4; j++) acc[i][j] = (f4v){0.f, 0.f, 0.f, 0.f};

  const int wm = (wave >> 1) * 64, wn = (wave & 1) * 64;

  auto stageA = [&](int kc, int db){
    int k = kc * 64;
#pragma unroll
    for (int cc = 0; cc < 2; cc++)
#pragma unroll
      for (int half = 0; half < 2; half++){
        int rb = wave * 32 + half * 16;
        gld16(A + (size_t)(m0 + rb + rsub) * DIMK + k + cc * 32 + cof,
              &sA[db][cc][rb * 32]);
      }
  };

  stageA(0, 0);
  __syncthreads();

  for (int kc = 0; kc < 16; kc++){
    const int db = kc & 1;
    if (kc + 1 < 16) stageA(kc + 1, db ^ 1);

    // B fragments direct from global (no LDS, no barrier dependency)
    s8v bfr[2][4];
#pragma unroll
    for (int cc = 0; cc < 2; cc++)
#pragma unroll
      for (int j = 0; j < 4; j++)
        bfr[cc][j] = *(const s8v*)(B + (size_t)(n0 + wn + j * 16 + lm) * DIMK
                                     + kc * 64 + cc * 32 + quad * 8);

#pragma unroll
    for (int cc = 0; cc < 2; cc++){
      s8v ah[4];
#pragma unroll
      for (int i = 0; i < 4; i++)
        ah[i] = *(const s8v*)&sA[db][cc][(wm + i * 16 + lm) * 32 + quad * 8];
#pragma unroll
      for (int i = 0; i < 4; i++)
#pragma unroll
        for (int j = 0; j < 4; j++)
          acc[i][j] = MFMA16(ah[i], bfr[cc][j], acc[i][j]);
    }
    __syncthreads();   // drains prefetch DMA (issued one compute-phase ago)
  }

  // epilogue: C/D layout col = lane&15, row = quad*4+reg  [m89-verified]
  if (mode == 1){
#pragma unroll
    for (int i = 0; i < 4; i++)
#pragma unroll
      for (int j = 0; j < 4; j++){
        int gn = n0 + wn + j * 16 + lm;
        float bv = bias[gn];
#pragma unroll
        for (int r = 0; r < 4; r++){
          int gm = m0 + wm + i * 16 + quad * 4 + r;
          Cf[(size_t)gm * DIMK + gn] = acc[i][j][r] + bv;
        }
      }
  } else {
#pragma unroll
    for (int i = 0; i < 4; i++)
#pragma unroll
      for (int j = 0; j < 4; j++){
        int gn = n0 + wn + j * 16 + lm;
#pragma unroll
        for (int r = 0; r < 4; r++){
          int gm = m0 + wm + i * 16 + quad * 4 + r;
          float v = acc[i][j][r];
          if (gn < 1024){                       // Q, token-major, pre-scaled
            Qh[(size_t)gm * DIMK + gn] = f2bf(v * QPRE);
          } else if (gn < 2048){                // K, token-major
            Kh[(size_t)gm * DIMK + (gn - 1024)] = f2bf(v);
          } else {                              // V^T with sigma permutation per 32-block
            int df = gn - 2048;
            int hh = df >> 6, dd = df & 63;
            int bb = gm >> 11, ii = gm & 2047;
            int ip = (ii & ~31) | (((ii & 15) << 1) | ((ii >> 4) & 1));
            Vth[(size_t)((bb * NH + hh) * DH + dd) * SEQ + ip] = f2bf(v);
          }
        }
      }
  }
}

// ---- flash attention, max-free softmax, double-buffered K/V ----
// one (b, h, 128-row q-tile) per block; 4 waves x 32 q-rows; Q (prescaled) in regs.
// K/V staged via gld16 into 2 buffers: stage(kt+1) issued before compute(kt),
// ONE barrier per kt — the S/exp/PV phase (~1500 cyc) covers the DMA latency.
// P = exp2(S) directly; l deferred (per-lane raw partials); P truncated+packed
// via v_perm into wave-private sP (no barrier needed for P).
__global__ __launch_bounds__(256, 3) void k_attn(
    const u16* __restrict__ Qh, const u16* __restrict__ Kh, const u16* __restrict__ Vth,
    u16* __restrict__ Oh)
{
  __shared__ u16 sK[2][2*64*32];   // [dbuf][c][j(64)][32]   16 KB
  __shared__ u16 sV[2][2*64*32];   // [dbuf][c][d(64)][32 j] 16 KB
  __shared__ u16 sP[2*128*32];     // [jc][i(128)][32 j-sigma] 16 KB
  u32* sPd = (u32*)sP;

  // XCD-aware (b,h,qt) assignment: all 16 q-tiles of one (b,h) on one XCD
  const int bid = blockIdx.x;
  const int xcd = bid & 7, slot = bid >> 3;
  const int g = xcd * 8 + (slot >> 4);           // (b,h) group 0..63
  const int qt = slot & 15;
  const int b = g >> 4, h = g & 15;

  const int tid = threadIdx.x, wave = tid >> 6, lane = tid & 63;
  const int lm = lane & 15, quad = lane >> 4;
  const int tok0 = b * SEQ + qt * 128;
  const int cof = (lane & 3) * 8;
  const int rsub = lane >> 2;

  // Q fragments straight to registers
  s8v qf[2][2];   // [c][ifr]
#pragma unroll
  for (int c = 0; c < 2; c++)
#pragma unroll
    for (int ifr = 0; ifr < 2; ifr++){
      size_t ga = (size_t)(tok0 + wave * 32 + ifr * 16 + lm) * DIMK + h * DH + c * 32 + quad * 8;
      qf[c][ifr] = *(const s8v*)(Qh + ga);
    }

  const f4v fz = (f4v){0.f, 0.f, 0.f, 0.f};   // persistent zero C-operand

  float lpart[2][4];
  f4v oacc[2][4];
#pragma unroll
  for (int ifr = 0; ifr < 2; ifr++){
#pragma unroll
    for (int r = 0; r < 4; r++) lpart[ifr][r] = 0.f;
#pragma unroll
    for (int fd = 0; fd < 4; fd++) oacc[ifr][fd] = (f4v){0.f, 0.f, 0.f, 0.f};
  }

  auto stageKV = [&](int kt, int db){
    int j0 = kt * 64;
#pragma unroll
    for (int c = 0; c < 2; c++){
      size_t gk = (size_t)(b * SEQ + j0 + wave * 16 + rsub) * DIMK + h * DH + c * 32 + cof;
      gld16(Kh + gk, &sK[db][c * 2048 + wave * 512]);
      size_t gv = (size_t)((b * NH + h) * DH + wave * 16 + rsub) * SEQ + j0 + c * 32 + cof;
      gld16(Vth + gv, &sV[db][c * 2048 + wave * 512]);
    }
  };

  stageKV(0, 0);
  __syncthreads();

  for (int kt = 0; kt < 32; kt++){
    const int db = kt & 1;
    if (kt + 1 < 32) stageKV(kt + 1, db ^ 1);

    // S' = Q' K^T (log2-scaled); first MFMA seeds from fz — no zero-init movs
    f4v s[2][4];
#pragma unroll
    for (int fn = 0; fn < 4; fn++){
      s8v kh0 = *(const s8v*)&sK[db][0 * 2048 + (fn * 16 + lm) * 32 + quad * 8];
      s8v kh1 = *(const s8v*)&sK[db][1 * 2048 + (fn * 16 + lm) * 32 + quad * 8];
#pragma unroll
      for (int ifr = 0; ifr < 2; ifr++){
        s[ifr][fn] = MFMA16(qf[0][ifr], kh0, fz);
        s[ifr][fn] = MFMA16(qf[1][ifr], kh1, s[ifr][fn]);
      }
    }

    // P = exp2(S'); raw-sum into l-partials; truncate+pack via v_perm, store
#pragma unroll
    for (int ifr = 0; ifr < 2; ifr++){
#pragma unroll
      for (int fn = 0; fn < 4; fn++)
#pragma unroll
        for (int r = 0; r < 4; r++)
          s[ifr][fn][r] = EXP2(s[ifr][fn][r]);
      int rowb = wave * 32 + ifr * 16 + quad * 4;
#pragma unroll
      for (int r = 0; r < 4; r++)
#pragma unroll
        for (int jc = 0; jc < 2; jc++){
          union { float f; u32 u; } a0, a1;
          a0.f = s[ifr][jc * 2 + 0][r];
          a1.f = s[ifr][jc * 2 + 1][r];
          lpart[ifr][r] += a0.f + a1.f;
          sPd[jc * 2048 + (rowb + r) * 16 + lm] = __builtin_amdgcn_perm(a1.u, a0.u, 0x07060302);
        }
    }

    // O += P V   (A = own wave's P rows; B = sigma-permuted Vt — consistent j order)
#pragma unroll
    for (int c = 0; c < 2; c++)
#pragma unroll
      for (int ifr = 0; ifr < 2; ifr++){
        s8v ph = *(const s8v*)&sP[c * 4096 + (wave * 32 + ifr * 16 + lm) * 32 + quad * 8];
#pragma unroll
        for (int fd = 0; fd < 4; fd++){
          s8v vh = *(const s8v*)&sV[db][c * 2048 + (fd * 16 + lm) * 32 + quad * 8];
          oacc[ifr][fd] = MFMA16(ph, vh, oacc[ifr][fd]);
        }
      }
    __syncthreads();   // drains prefetch DMA; protects dbuf write-after-read
  }

  // final l reduction (within each 16-lane group) + normalize + store
#pragma unroll
  for (int ifr = 0; ifr < 2; ifr++){
#pragma unroll
    for (int off = 1; off < 16; off <<= 1)
#pragma unroll
      for (int r = 0; r < 4; r++)
        lpart[ifr][r] += __shfl_xor(lpart[ifr][r], off, 64);
    float inv[4];
#pragma unroll
    for (int r = 0; r < 4; r++) inv[r] = 1.f / lpart[ifr][r];
#pragma unroll
    for (int fd = 0; fd < 4; fd++){
      int dcol = h * DH + fd * 16 + lm;
#pragma unroll
      for (int r = 0; r < 4; r++){
        int tok = tok0 + wave * 32 + ifr * 16 + quad * 4 + r;
        Oh[(size_t)tok * DIMK + dcol] = f2bf(oacc[ifr][fd][r] * inv[r]);
      }
    }
  }
}

extern "C" void kernel_launch(void* const* d_in, const int* in_sizes, int n_in,
                              void* d_out, int out_size, void* d_ws, size_t ws_size,
                              hipStream_t stream) {
  const float* x   = (const float*)d_in[0];
  const float* Wq  = (const float*)d_in[1];
  const float* Wkv = (const float*)d_in[2];
  const float* Wo  = (const float*)d_in[3];
  const float* bo  = (const float*)d_in[4];
  float* out = (float*)d_out;

  char* ws = (char*)d_ws;
  size_t off = 0;
  auto alloc = [&](size_t bytes) -> u16* {
    u16* p = (u16*)(ws + off);
    off += (bytes + 255) & ~(size_t)255;
    return p;
  };
  const size_t TK2 = (size_t)TOKENS * DIMK * 2;   // 16.78 MB per bf16 plane
  u16* xh  = alloc(TK2);
  u16* Wh  = alloc((size_t)3072 * DIMK * 2);      // [Wq|Wkv]^T  [3072][1024]
  u16* WOh = alloc((size_t)1024 * DIMK * 2);      // Wo^T        [1024][1024]
  u16* Qh  = alloc(TK2);
  u16* Kh  = alloc(TK2);
  u16* Vth = alloc(TK2);
  u16* Oh  = alloc(TK2);

  // 1) cast x to bf16
  k_cast<<<dim3((TOKENS * DIMK) / 1024), 256, 0, stream>>>(x, xh);
  // 2) transpose weights to n-major
  k_transpose<<<dim3(48, 16), 256, 0, stream>>>(Wq, 1024, Wkv, 2048, DIMK, Wh);
  k_transpose<<<dim3(16, 16), 256, 0, stream>>>(Wo, 1024, Wo, 1024, DIMK, WOh);
  // 3) QKV projection (N=3072): n-partition swizzle (B-band L2-resident)
  k_gemm<<<dim3(24 * 64), 256, 0, stream>>>(xh, Wh, 24, 0, 0, nullptr, nullptr,
                                            Qh, Kh, Vth);
  // 4) flash attention (max-free softmax, K/V dbuf), XCD-grouped
  k_attn<<<dim3(16 * NH * 4), 256, 0, stream>>>(Qh, Kh, Vth, Oh);
  // 5) output projection + bias: m-partition swizzle (A-band L2-resident)
  k_gemm<<<dim3(8 * 64), 256, 0, stream>>>(Oh, WOh, 8, 1, 1, bo, out,
                                           nullptr, nullptr, nullptr);
}

// Round 7
// 319.134 us; speedup vs baseline: 1.1700x; 1.1700x over previous
//
#include <hip/hip_runtime.h>
#include <hip/hip_bf16.h>

typedef unsigned short u16;
typedef unsigned int u32;
typedef __attribute__((ext_vector_type(8))) short s8v;    // 8 bf16 (4 VGPRs) — MFMA A/B frag
typedef __attribute__((ext_vector_type(4))) float f4v;    // MFMA C/D frag
typedef __attribute__((ext_vector_type(4))) unsigned short u16x4;

#define MFMA16(a,b,c) __builtin_amdgcn_mfma_f32_16x16x32_bf16((a),(b),(c),0,0,0)

#define TOKENS 8192        // 4 * 2048
#define SEQ    2048
#define NH     16
#define DH     64
#define DIMK   1024
// fold 1/sqrt(64) * log2(e) into Q so P = exp2(S) directly
#define QPRE   0.18033688f

#if defined(__has_builtin)
#if __has_builtin(__builtin_amdgcn_exp2f)
#define EXP2(x) __builtin_amdgcn_exp2f(x)
#else
#define EXP2(x) __expf((x) * 0.69314718f)
#endif
#else
#define EXP2(x) __expf((x) * 0.69314718f)
#endif

// ---- bf16 helpers (round-to-nearest-even) ----
__device__ __forceinline__ u16 f2bf(float x){
  union { float f; u32 u; } v; v.f = x;
  u32 r = v.u + 0x7FFFu + ((v.u >> 16) & 1u);
  return (u16)(r >> 16);
}

// async global->LDS, 16B per lane; LDS dest = wave-uniform base + lane*16
__device__ __forceinline__ void gld16(const u16* g, u16* s){
  __builtin_amdgcn_global_load_lds(
      (const __attribute__((address_space(1))) unsigned int*)(const void*)g,
      (__attribute__((address_space(3))) unsigned int*)(void*)s,
      16, 0, 0);
}

// ---- cast fp32 -> bf16 (x) ----
__global__ __launch_bounds__(256) void k_cast(const float* __restrict__ src,
                                              u16* __restrict__ dst){
  int i = (blockIdx.x * 256 + threadIdx.x) * 4;
  float4 v = *(const float4*)(src + i);
  u16x4 vh;
  float a[4] = {v.x, v.y, v.z, v.w};
#pragma unroll
  for (int j = 0; j < 4; j++) vh[j] = f2bf(a[j]);
  *(u16x4*)(dst + i) = vh;
}

// ---- transpose weights to n-major bf16: out[n][k] = src[k][n] ----
__global__ __launch_bounds__(256) void k_transpose(const float* __restrict__ s0, int c0,
                                                   const float* __restrict__ s1, int c1,
                                                   int K, u16* __restrict__ dh){
  __shared__ float tile[64][65];
  int nb = blockIdx.x * 64, kb = blockIdx.y * 64;
  int tr = threadIdx.x >> 6, tc = threadIdx.x & 63;
#pragma unroll
  for (int i = 0; i < 16; i++){
    int k = kb + tr + i * 4, n = nb + tc;
    float v = (n < c0) ? s0[(size_t)k * c0 + n] : s1[(size_t)k * c1 + (n - c0)];
    tile[tr + i * 4][tc] = v;
  }
  __syncthreads();
#pragma unroll
  for (int i = 0; i < 16; i++){
    int nl = tr + i * 4, kl = tc;
    dh[(size_t)(nb + nl) * K + (kb + kl)] = f2bf(tile[kl][nl]);
  }
}

// ---- QKV GEMM: big-tile BM=256 x BN=128, BK=64, 256 threads ----
// Wave-tile 64x128 (acc 4x8). Per barrier-pair: 64 MFMA + 24 ds_read_b128
// (~900 cyc compute) vs the ~600 cyc vmcnt(0) drain -> ~2x busy fraction of
// the 128-tile version; staged bytes 768->576 MB. LDS 48 KB single-buffered.
// XCD swizzle: each XCD owns 3 consecutive n-tiles (B-band 768 KB L2-resident)
// and sweeps m; 3 x-neighbors sharing an A-tile are dispatch-adjacent.
// Epilogue routes cols: Q (prescaled) / K token-major, V^T + sigma perm.
__global__ __launch_bounds__(256, 2) void k_gemm_qkv(
    const u16* __restrict__ A, const u16* __restrict__ B,
    u16* __restrict__ Qh, u16* __restrict__ Kh, u16* __restrict__ Vth)
{
  __shared__ u16 sA[2][256*32];   // [cc][row*32] 32 KB
  __shared__ u16 sB[2][128*32];   // [cc][row*32] 16 KB
  const int tid = threadIdx.x, wave = tid >> 6, lane = tid & 63;
  const int lm = lane & 15, quad = lane >> 4;

  // XCD-aware tile assignment: nx=24, 3 n-tiles per XCD
  const int bid = blockIdx.x;
  const int xcd = bid & 7, slot = bid >> 3;        // slot 0..95
  const int xt = xcd * 3 + slot % 3;               // 0..23
  const int yt = slot / 3;                         // 0..31
  const int m0 = yt * 256, n0 = xt * 128;

  const int cof = (lane & 3) * 8;
  const int rsub = lane >> 2;

  f4v acc[4][8];
#pragma unroll
  for (int i = 0; i < 4; i++)
#pragma unroll
    for (int j = 0; j < 8; j++) acc[i][j] = (f4v){0.f, 0.f, 0.f, 0.f};

  for (int kc = 0; kc < 16; kc++){
    int k = kc * 64;
    // stage A (256 rows) + B (128 rows), 12 gld16/thread = 48 KB
#pragma unroll
    for (int cc = 0; cc < 2; cc++){
#pragma unroll
      for (int half = 0; half < 4; half++){
        int rb = wave * 64 + half * 16;
        gld16(A + (size_t)(m0 + rb + rsub) * DIMK + k + cc * 32 + cof, &sA[cc][rb * 32]);
      }
#pragma unroll
      for (int half = 0; half < 2; half++){
        int rb = wave * 32 + half * 16;
        gld16(B + (size_t)(n0 + rb + rsub) * DIMK + k + cc * 32 + cof, &sB[cc][rb * 32]);
      }
    }
    __syncthreads();

#pragma unroll
    for (int cc = 0; cc < 2; cc++){
      s8v ah[4], bh[8];
#pragma unroll
      for (int i = 0; i < 4; i++)
        ah[i] = *(const s8v*)&sA[cc][(wave * 64 + i * 16 + lm) * 32 + quad * 8];
#pragma unroll
      for (int j = 0; j < 8; j++)
        bh[j] = *(const s8v*)&sB[cc][(j * 16 + lm) * 32 + quad * 8];
#pragma unroll
      for (int i = 0; i < 4; i++)
#pragma unroll
        for (int j = 0; j < 8; j++)
          acc[i][j] = MFMA16(ah[i], bh[j], acc[i][j]);
    }
    __syncthreads();
  }

  // epilogue: C/D layout col = lane&15, row = quad*4+reg  [m89-verified]
#pragma unroll
  for (int i = 0; i < 4; i++)
#pragma unroll
    for (int j = 0; j < 8; j++){
      int gn = n0 + j * 16 + lm;
#pragma unroll
      for (int r = 0; r < 4; r++){
        int gm = m0 + wave * 64 + i * 16 + quad * 4 + r;
        float v = acc[i][j][r];
        if (gn < 1024){                       // Q, token-major, pre-scaled
          Qh[(size_t)gm * DIMK + gn] = f2bf(v * QPRE);
        } else if (gn < 2048){                // K, token-major
          Kh[(size_t)gm * DIMK + (gn - 1024)] = f2bf(v);
        } else {                              // V^T with sigma permutation per 32-block
          int df = gn - 2048;
          int hh = df >> 6, dd = df & 63;
          int bb = gm >> 11, ii = gm & 2047;
          int ip = (ii & ~31) | (((ii & 15) << 1) | ((ii >> 4) & 1));
          Vth[(size_t)((bb * NH + hh) * DH + dd) * SEQ + ip] = f2bf(v);
        }
      }
    }
}

// ---- out-proj GEMM: 128x128, BK=64, natural 2D grid (R4/R5-proven) ----
__global__ __launch_bounds__(256) void k_gemm_op(
    const u16* __restrict__ A, const u16* __restrict__ B,
    const float* __restrict__ bias, float* __restrict__ Cf)
{
  __shared__ u16 sA[2][128*32], sB[2][128*32];   // 32 KB
  const int tid = threadIdx.x, wave = tid >> 6, lane = tid & 63;
  const int lm = lane & 15, quad = lane >> 4;
  const int m0 = blockIdx.y * 128, n0 = blockIdx.x * 128;
  const int cof = (lane & 3) * 8;
  const int rsub = lane >> 2;

  f4v acc[4][4];
#pragma unroll
  for (int i = 0; i < 4; i++)
#pragma unroll
    for (int j = 0; j < 4; j++) acc[i][j] = (f4v){0.f, 0.f, 0.f, 0.f};

  const int wm = (wave >> 1) * 64, wn = (wave & 1) * 64;

  for (int kc = 0; kc < 16; kc++){
    int k = kc * 64;
#pragma unroll
    for (int cc = 0; cc < 2; cc++)
#pragma unroll
      for (int half = 0; half < 2; half++){
        int rb = wave * 32 + half * 16;
        gld16(A + (size_t)(m0 + rb + rsub) * DIMK + k + cc * 32 + cof, &sA[cc][rb * 32]);
        gld16(B + (size_t)(n0 + rb + rsub) * DIMK + k + cc * 32 + cof, &sB[cc][rb * 32]);
      }
    __syncthreads();

#pragma unroll
    for (int cc = 0; cc < 2; cc++){
      s8v ah[4], bh[4];
#pragma unroll
      for (int i = 0; i < 4; i++){
        ah[i] = *(const s8v*)&sA[cc][(wm + i * 16 + lm) * 32 + quad * 8];
        bh[i] = *(const s8v*)&sB[cc][(wn + i * 16 + lm) * 32 + quad * 8];
      }
#pragma unroll
      for (int i = 0; i < 4; i++)
#pragma unroll
        for (int j = 0; j < 4; j++)
          acc[i][j] = MFMA16(ah[i], bh[j], acc[i][j]);
    }
    __syncthreads();
  }

#pragma unroll
  for (int i = 0; i < 4; i++)
#pragma unroll
    for (int j = 0; j < 4; j++){
      int gn = n0 + wn + j * 16 + lm;
      float bv = bias[gn];
#pragma unroll
      for (int r = 0; r < 4; r++){
        int gm = m0 + wm + i * 16 + quad * 4 + r;
        Cf[(size_t)gm * DIMK + gn] = acc[i][j][r] + bv;
      }
    }
}

// ---- flash attention, max-free softmax (R4-proven form) ----
// one (b, h, 128-row q-tile) per block; 4 waves x 32 q-rows; Q (prescaled) in regs.
// P = exp2(S) directly; S seeded from persistent zero fragment; l deferred
// (per-lane raw partials); P truncated+packed via v_perm into wave-private sP.
__global__ __launch_bounds__(256, 4) void k_attn(
    const u16* __restrict__ Qh, const u16* __restrict__ Kh, const u16* __restrict__ Vth,
    u16* __restrict__ Oh)
{
  __shared__ u16 sK[2*64*32];      // [c][j(64)][32]   8 KB
  __shared__ u16 sV[2*64*32];      // [c][d(64)][32 j] 8 KB
  __shared__ u16 sP[2*128*32];     // [jc][i(128)][32 j-sigma] 16 KB
  u32* sPd = (u32*)sP;

  const int qt = blockIdx.x, h = blockIdx.y, b = blockIdx.z;
  const int tid = threadIdx.x, wave = tid >> 6, lane = tid & 63;
  const int lm = lane & 15, quad = lane >> 4;
  const int tok0 = b * SEQ + qt * 128;
  const int cof = (lane & 3) * 8;
  const int rsub = lane >> 2;

  // Q fragments straight to registers
  s8v qf[2][2];   // [c][ifr]
#pragma unroll
  for (int c = 0; c < 2; c++)
#pragma unroll
    for (int ifr = 0; ifr < 2; ifr++){
      size_t ga = (size_t)(tok0 + wave * 32 + ifr * 16 + lm) * DIMK + h * DH + c * 32 + quad * 8;
      qf[c][ifr] = *(const s8v*)(Qh + ga);
    }

  const f4v fz = (f4v){0.f, 0.f, 0.f, 0.f};   // persistent zero C-operand

  float lpart[2][4];
  f4v oacc[2][4];
#pragma unroll
  for (int ifr = 0; ifr < 2; ifr++){
#pragma unroll
    for (int r = 0; r < 4; r++) lpart[ifr][r] = 0.f;
#pragma unroll
    for (int fd = 0; fd < 4; fd++) oacc[ifr][fd] = (f4v){0.f, 0.f, 0.f, 0.f};
  }

  for (int kt = 0; kt < 32; kt++){
    int j0 = kt * 64;
#pragma unroll
    for (int c = 0; c < 2; c++){
      size_t gk = (size_t)(b * SEQ + j0 + wave * 16 + rsub) * DIMK + h * DH + c * 32 + cof;
      gld16(Kh + gk, &sK[c * 2048 + wave * 512]);
      size_t gv = (size_t)((b * NH + h) * DH + wave * 16 + rsub) * SEQ + j0 + c * 32 + cof;
      gld16(Vth + gv, &sV[c * 2048 + wave * 512]);
    }
    __syncthreads();

    // S' = Q' K^T (log2-scaled); first MFMA seeds from fz — no zero-init movs
    f4v s[2][4];
#pragma unroll
    for (int fn = 0; fn < 4; fn++){
      s8v kh0 = *(const s8v*)&sK[0 * 2048 + (fn * 16 + lm) * 32 + quad * 8];
      s8v kh1 = *(const s8v*)&sK[1 * 2048 + (fn * 16 + lm) * 32 + quad * 8];
#pragma unroll
      for (int ifr = 0; ifr < 2; ifr++){
        s[ifr][fn] = MFMA16(qf[0][ifr], kh0, fz);
        s[ifr][fn] = MFMA16(qf[1][ifr], kh1, s[ifr][fn]);
      }
    }

    // P = exp2(S'); raw-sum into l-partials; truncate+pack via v_perm, store
#pragma unroll
    for (int ifr = 0; ifr < 2; ifr++){
#pragma unroll
      for (int fn = 0; fn < 4; fn++)
#pragma unroll
        for (int r = 0; r < 4; r++)
          s[ifr][fn][r] = EXP2(s[ifr][fn][r]);
      int rowb = wave * 32 + ifr * 16 + quad * 4;
#pragma unroll
      for (int r = 0; r < 4; r++)
#pragma unroll
        for (int jc = 0; jc < 2; jc++){
          union { float f; u32 u; } a0, a1;
          a0.f = s[ifr][jc * 2 + 0][r];
          a1.f = s[ifr][jc * 2 + 1][r];
          lpart[ifr][r] += a0.f + a1.f;
          sPd[jc * 2048 + (rowb + r) * 16 + lm] = __builtin_amdgcn_perm(a1.u, a0.u, 0x07060302);
        }
    }

    // O += P V   (A = own wave's P rows; B = sigma-permuted Vt — consistent j order)
#pragma unroll
    for (int c = 0; c < 2; c++)
#pragma unroll
      for (int ifr = 0; ifr < 2; ifr++){
        s8v ph = *(const s8v*)&sP[c * 4096 + (wave * 32 + ifr * 16 + lm) * 32 + quad * 8];
#pragma unroll
        for (int fd = 0; fd < 4; fd++){
          s8v vh = *(const s8v*)&sV[c * 2048 + (fd * 16 + lm) * 32 + quad * 8];
          oacc[ifr][fd] = MFMA16(ph, vh, oacc[ifr][fd]);
        }
      }
    __syncthreads();   // all waves done reading sK/sV before next staging
  }

  // final l reduction (within each 16-lane group) + normalize + store
#pragma unroll
  for (int ifr = 0; ifr < 2; ifr++){
#pragma unroll
    for (int off = 1; off < 16; off <<= 1)
#pragma unroll
      for (int r = 0; r < 4; r++)
        lpart[ifr][r] += __shfl_xor(lpart[ifr][r], off, 64);
    float inv[4];
#pragma unroll
    for (int r = 0; r < 4; r++) inv[r] = 1.f / lpart[ifr][r];
#pragma unroll
    for (int fd = 0; fd < 4; fd++){
      int dcol = h * DH + fd * 16 + lm;
#pragma unroll
      for (int r = 0; r < 4; r++){
        int tok = tok0 + wave * 32 + ifr * 16 + quad * 4 + r;
        Oh[(size_t)tok * DIMK + dcol] = f2bf(oacc[ifr][fd][r] * inv[r]);
      }
    }
  }
}

extern "C" void kernel_launch(void* const* d_in, const int* in_sizes, int n_in,
                              void* d_out, int out_size, void* d_ws, size_t ws_size,
                              hipStream_t stream) {
  const float* x   = (const float*)d_in[0];
  const float* Wq  = (const float*)d_in[1];
  const float* Wkv = (const float*)d_in[2];
  const float* Wo  = (const float*)d_in[3];
  const float* bo  = (const float*)d_in[4];
  float* out = (float*)d_out;

  char* ws = (char*)d_ws;
  size_t off = 0;
  auto alloc = [&](size_t bytes) -> u16* {
    u16* p = (u16*)(ws + off);
    off += (bytes + 255) & ~(size_t)255;
    return p;
  };
  const size_t TK2 = (size_t)TOKENS * DIMK * 2;   // 16.78 MB per bf16 plane
  u16* xh  = alloc(TK2);
  u16* Wh  = alloc((size_t)3072 * DIMK * 2);      // [Wq|Wkv]^T  [3072][1024]
  u16* WOh = alloc((size_t)1024 * DIMK * 2);      // Wo^T        [1024][1024]
  u16* Qh  = alloc(TK2);
  u16* Kh  = alloc(TK2);
  u16* Vth = alloc(TK2);
  u16* Oh  = alloc(TK2);

  // 1) cast x to bf16
  k_cast<<<dim3((TOKENS * DIMK) / 1024), 256, 0, stream>>>(x, xh);
  // 2) transpose weights to n-major
  k_transpose<<<dim3(48, 16), 256, 0, stream>>>(Wq, 1024, Wkv, 2048, DIMK, Wh);
  k_transpose<<<dim3(16, 16), 256, 0, stream>>>(Wo, 1024, Wo, 1024, DIMK, WOh);
  // 3) QKV projection (N=3072): big-tile 256x128, XCD n-partition swizzle
  k_gemm_qkv<<<dim3(24 * 32), 256, 0, stream>>>(xh, Wh, Qh, Kh, Vth);
  // 4) flash attention (max-free softmax), R4 mapping
  k_attn<<<dim3(16, NH, 4), 256, 0, stream>>>(Qh, Kh, Vth, Oh);
  // 5) output projection + bias, fp32 out
  k_gemm_op<<<dim3(8, 64), 256, 0, stream>>>(Oh, WOh, bo, out);
}

// Round 8
// 302.063 us; speedup vs baseline: 1.2361x; 1.0565x over previous
//
#include <hip/hip_runtime.h>
#include <hip/hip_bf16.h>

typedef unsigned short u16;
typedef unsigned int u32;
typedef __attribute__((ext_vector_type(8))) short s8v;    // 8 bf16 (4 VGPRs) — MFMA A/B frag
typedef __attribute__((ext_vector_type(4))) float f4v;    // MFMA C/D frag
typedef __attribute__((ext_vector_type(4))) unsigned short u16x4;

#define MFMA16(a,b,c) __builtin_amdgcn_mfma_f32_16x16x32_bf16((a),(b),(c),0,0,0)

#define TOKENS 8192        // 4 * 2048
#define SEQ    2048
#define NH     16
#define DH     64
#define DIMK   1024
// fold 1/sqrt(64) * log2(e) into Q so P = exp2(S) directly
#define QPRE   0.18033688f

#if defined(__has_builtin)
#if __has_builtin(__builtin_amdgcn_exp2f)
#define EXP2(x) __builtin_amdgcn_exp2f(x)
#else
#define EXP2(x) __expf((x) * 0.69314718f)
#endif
#else
#define EXP2(x) __expf((x) * 0.69314718f)
#endif

// ---- bf16 helpers (round-to-nearest-even) ----
__device__ __forceinline__ u16 f2bf(float x){
  union { float f; u32 u; } v; v.f = x;
  u32 r = v.u + 0x7FFFu + ((v.u >> 16) & 1u);
  return (u16)(r >> 16);
}

// async global->LDS, 16B per lane; LDS dest = wave-uniform base + lane*16
__device__ __forceinline__ void gld16(const u16* g, u16* s){
  __builtin_amdgcn_global_load_lds(
      (const __attribute__((address_space(1))) unsigned int*)(const void*)g,
      (__attribute__((address_space(3))) unsigned int*)(void*)s,
      16, 0, 0);
}

// ---- cast fp32 -> bf16 (x) ----
__global__ __launch_bounds__(256) void k_cast(const float* __restrict__ src,
                                              u16* __restrict__ dst){
  int i = (blockIdx.x * 256 + threadIdx.x) * 4;
  float4 v = *(const float4*)(src + i);
  u16x4 vh;
  float a[4] = {v.x, v.y, v.z, v.w};
#pragma unroll
  for (int j = 0; j < 4; j++) vh[j] = f2bf(a[j]);
  *(u16x4*)(dst + i) = vh;
}

// ---- transpose weights to n-major bf16: out[n][k] = src[k][n] ----
__global__ __launch_bounds__(256) void k_transpose(const float* __restrict__ s0, int c0,
                                                   const float* __restrict__ s1, int c1,
                                                   int K, u16* __restrict__ dh){
  __shared__ float tile[64][65];
  int nb = blockIdx.x * 64, kb = blockIdx.y * 64;
  int tr = threadIdx.x >> 6, tc = threadIdx.x & 63;
#pragma unroll
  for (int i = 0; i < 16; i++){
    int k = kb + tr + i * 4, n = nb + tc;
    float v = (n < c0) ? s0[(size_t)k * c0 + n] : s1[(size_t)k * c1 + (n - c0)];
    tile[tr + i * 4][tc] = v;
  }
  __syncthreads();
#pragma unroll
  for (int i = 0; i < 16; i++){
    int nl = tr + i * 4, kl = tc;
    dh[(size_t)(nb + nl) * K + (kb + kl)] = f2bf(tile[kl][nl]);
  }
}

// ---- QKV GEMM: BM=256 x BN=128, BK=64, 256 threads, 3 blocks/CU ----
// L2-residency swizzle (L3-BW is the measured wall at ~5-7 TB/s):
// XCD owns 4 consecutive 256-row m-tiles -> its A-band (2 MB) is L2-resident
// across the whole n-sweep. slot = n*4 + mloc: each 256 KB B-tile is read by
// the XCD's 4 concurrent m-blocks then retired (resident B set <= 4 MB = L2).
// L3-level traffic ~570 MB -> ~70 MB.
__global__ __launch_bounds__(256, 3) void k_gemm_qkv(
    const u16* __restrict__ A, const u16* __restrict__ B,
    u16* __restrict__ Qh, u16* __restrict__ Kh, u16* __restrict__ Vth)
{
  __shared__ u16 sA[2][256*32];   // [cc][row*32] 32 KB
  __shared__ u16 sB[2][128*32];   // [cc][row*32] 16 KB
  const int tid = threadIdx.x, wave = tid >> 6, lane = tid & 63;
  const int lm = lane & 15, quad = lane >> 4;

  // m-partition XCD swizzle: xcd owns m-tiles [xcd*4, xcd*4+4)
  const int bid = blockIdx.x;
  const int xcd = bid & 7, slot = bid >> 3;        // slot 0..95
  const int nt = slot >> 2;                        // 0..23
  const int mloc = slot & 3;                       // 0..3
  const int m0 = (xcd * 4 + mloc) * 256, n0 = nt * 128;

  const int cof = (lane & 3) * 8;
  const int rsub = lane >> 2;

  f4v acc[4][8];
#pragma unroll
  for (int i = 0; i < 4; i++)
#pragma unroll
    for (int j = 0; j < 8; j++) acc[i][j] = (f4v){0.f, 0.f, 0.f, 0.f};

  for (int kc = 0; kc < 16; kc++){
    int k = kc * 64;
    // stage A (256 rows) + B (128 rows), 12 gld16/thread = 48 KB
#pragma unroll
    for (int cc = 0; cc < 2; cc++){
#pragma unroll
      for (int half = 0; half < 4; half++){
        int rb = wave * 64 + half * 16;
        gld16(A + (size_t)(m0 + rb + rsub) * DIMK + k + cc * 32 + cof, &sA[cc][rb * 32]);
      }
#pragma unroll
      for (int half = 0; half < 2; half++){
        int rb = wave * 32 + half * 16;
        gld16(B + (size_t)(n0 + rb + rsub) * DIMK + k + cc * 32 + cof, &sB[cc][rb * 32]);
      }
    }
    __syncthreads();

#pragma unroll
    for (int cc = 0; cc < 2; cc++){
      s8v ah[4], bh[8];
#pragma unroll
      for (int i = 0; i < 4; i++)
        ah[i] = *(const s8v*)&sA[cc][(wave * 64 + i * 16 + lm) * 32 + quad * 8];
#pragma unroll
      for (int j = 0; j < 8; j++)
        bh[j] = *(const s8v*)&sB[cc][(j * 16 + lm) * 32 + quad * 8];
#pragma unroll
      for (int i = 0; i < 4; i++)
#pragma unroll
        for (int j = 0; j < 8; j++)
          acc[i][j] = MFMA16(ah[i], bh[j], acc[i][j]);
    }
    __syncthreads();
  }

  // epilogue: C/D layout col = lane&15, row = quad*4+reg  [m89-verified]
#pragma unroll
  for (int i = 0; i < 4; i++)
#pragma unroll
    for (int j = 0; j < 8; j++){
      int gn = n0 + j * 16 + lm;
#pragma unroll
      for (int r = 0; r < 4; r++){
        int gm = m0 + wave * 64 + i * 16 + quad * 4 + r;
        float v = acc[i][j][r];
        if (gn < 1024){                       // Q, token-major, pre-scaled
          Qh[(size_t)gm * DIMK + gn] = f2bf(v * QPRE);
        } else if (gn < 2048){                // K, token-major
          Kh[(size_t)gm * DIMK + (gn - 1024)] = f2bf(v);
        } else {                              // V^T with sigma permutation per 32-block
          int df = gn - 2048;
          int hh = df >> 6, dd = df & 63;
          int bb = gm >> 11, ii = gm & 2047;
          int ip = (ii & ~31) | (((ii & 15) << 1) | ((ii >> 4) & 1));
          Vth[(size_t)((bb * NH + hh) * DH + dd) * SEQ + ip] = f2bf(v);
        }
      }
    }
}

// ---- out-proj GEMM: 128x128, BK=64, m-partition XCD swizzle ----
// XCD owns 8 m-tiles (A-band 2 MB L2-resident), sweeps 8 n-tiles (B 2 MB).
__global__ __launch_bounds__(256) void k_gemm_op(
    const u16* __restrict__ A, const u16* __restrict__ B,
    const float* __restrict__ bias, float* __restrict__ Cf)
{
  __shared__ u16 sA[2][128*32], sB[2][128*32];   // 32 KB
  const int tid = threadIdx.x, wave = tid >> 6, lane = tid & 63;
  const int lm = lane & 15, quad = lane >> 4;

  const int bid = blockIdx.x;
  const int xcd = bid & 7, slot = bid >> 3;      // slot 0..63
  const int nt = slot >> 3, mloc = slot & 7;
  const int m0 = (xcd * 8 + mloc) * 128, n0 = nt * 128;

  const int cof = (lane & 3) * 8;
  const int rsub = lane >> 2;

  f4v acc[4][4];
#pragma unroll
  for (int i = 0; i < 4; i++)
#pragma unroll
    for (int j = 0; j < 4; j++) acc[i][j] = (f4v){0.f, 0.f, 0.f, 0.f};

  const int wm = (wave >> 1) * 64, wn = (wave & 1) * 64;

  for (int kc = 0; kc < 16; kc++){
    int k = kc * 64;
#pragma unroll
    for (int cc = 0; cc < 2; cc++)
#pragma unroll
      for (int half = 0; half < 2; half++){
        int rb = wave * 32 + half * 16;
        gld16(A + (size_t)(m0 + rb + rsub) * DIMK + k + cc * 32 + cof, &sA[cc][rb * 32]);
        gld16(B + (size_t)(n0 + rb + rsub) * DIMK + k + cc * 32 + cof, &sB[cc][rb * 32]);
      }
    __syncthreads();

#pragma unroll
    for (int cc = 0; cc < 2; cc++){
      s8v ah[4], bh[4];
#pragma unroll
      for (int i = 0; i < 4; i++){
        ah[i] = *(const s8v*)&sA[cc][(wm + i * 16 + lm) * 32 + quad * 8];
        bh[i] = *(const s8v*)&sB[cc][(wn + i * 16 + lm) * 32 + quad * 8];
      }
#pragma unroll
      for (int i = 0; i < 4; i++)
#pragma unroll
        for (int j = 0; j < 4; j++)
          acc[i][j] = MFMA16(ah[i], bh[j], acc[i][j]);
    }
    __syncthreads();
  }

#pragma unroll
  for (int i = 0; i < 4; i++)
#pragma unroll
    for (int j = 0; j < 4; j++){
      int gn = n0 + wn + j * 16 + lm;
      float bv = bias[gn];
#pragma unroll
      for (int r = 0; r < 4; r++){
        int gm = m0 + wm + i * 16 + quad * 4 + r;
        Cf[(size_t)gm * DIMK + gn] = acc[i][j][r] + bv;
      }
    }
}

// ---- flash attention, max-free softmax, XCD (b,h)-grouping ----
// All 16 q-tiles of one (b,h) — sharing a 512 KB K/V stream — on one XCD:
// KV L3 traffic 256 MB -> 33 MB. Kernel body is the R4/R7-proven form.
__global__ __launch_bounds__(256, 4) void k_attn(
    const u16* __restrict__ Qh, const u16* __restrict__ Kh, const u16* __restrict__ Vth,
    u16* __restrict__ Oh)
{
  __shared__ u16 sK[2*64*32];      // [c][j(64)][32]   8 KB
  __shared__ u16 sV[2*64*32];      // [c][d(64)][32 j] 8 KB
  __shared__ u16 sP[2*128*32];     // [jc][i(128)][32 j-sigma] 16 KB
  u32* sPd = (u32*)sP;

  // XCD-aware (b,h,qt) assignment
  const int bid = blockIdx.x;
  const int xcd = bid & 7, slot = bid >> 3;
  const int g = xcd * 8 + (slot >> 4);           // (b,h) group 0..63
  const int qt = slot & 15;
  const int b = g >> 4, h = g & 15;

  const int tid = threadIdx.x, wave = tid >> 6, lane = tid & 63;
  const int lm = lane & 15, quad = lane >> 4;
  const int tok0 = b * SEQ + qt * 128;
  const int cof = (lane & 3) * 8;
  const int rsub = lane >> 2;

  // Q fragments straight to registers
  s8v qf[2][2];   // [c][ifr]
#pragma unroll
  for (int c = 0; c < 2; c++)
#pragma unroll
    for (int ifr = 0; ifr < 2; ifr++){
      size_t ga = (size_t)(tok0 + wave * 32 + ifr * 16 + lm) * DIMK + h * DH + c * 32 + quad * 8;
      qf[c][ifr] = *(const s8v*)(Qh + ga);
    }

  const f4v fz = (f4v){0.f, 0.f, 0.f, 0.f};   // persistent zero C-operand

  float lpart[2][4];
  f4v oacc[2][4];
#pragma unroll
  for (int ifr = 0; ifr < 2; ifr++){
#pragma unroll
    for (int r = 0; r < 4; r++) lpart[ifr][r] = 0.f;
#pragma unroll
    for (int fd = 0; fd < 4; fd++) oacc[ifr][fd] = (f4v){0.f, 0.f, 0.f, 0.f};
  }

  for (int kt = 0; kt < 32; kt++){
    int j0 = kt * 64;
#pragma unroll
    for (int c = 0; c < 2; c++){
      size_t gk = (size_t)(b * SEQ + j0 + wave * 16 + rsub) * DIMK + h * DH + c * 32 + cof;
      gld16(Kh + gk, &sK[c * 2048 + wave * 512]);
      size_t gv = (size_t)((b * NH + h) * DH + wave * 16 + rsub) * SEQ + j0 + c * 32 + cof;
      gld16(Vth + gv, &sV[c * 2048 + wave * 512]);
    }
    __syncthreads();

    // S' = Q' K^T (log2-scaled); first MFMA seeds from fz — no zero-init movs
    f4v s[2][4];
#pragma unroll
    for (int fn = 0; fn < 4; fn++){
      s8v kh0 = *(const s8v*)&sK[0 * 2048 + (fn * 16 + lm) * 32 + quad * 8];
      s8v kh1 = *(const s8v*)&sK[1 * 2048 + (fn * 16 + lm) * 32 + quad * 8];
#pragma unroll
      for (int ifr = 0; ifr < 2; ifr++){
        s[ifr][fn] = MFMA16(qf[0][ifr], kh0, fz);
        s[ifr][fn] = MFMA16(qf[1][ifr], kh1, s[ifr][fn]);
      }
    }

    // P = exp2(S'); raw-sum into l-partials; truncate+pack via v_perm, store
#pragma unroll
    for (int ifr = 0; ifr < 2; ifr++){
#pragma unroll
      for (int fn = 0; fn < 4; fn++)
#pragma unroll
        for (int r = 0; r < 4; r++)
          s[ifr][fn][r] = EXP2(s[ifr][fn][r]);
      int rowb = wave * 32 + ifr * 16 + quad * 4;
#pragma unroll
      for (int r = 0; r < 4; r++)
#pragma unroll
        for (int jc = 0; jc < 2; jc++){
          union { float f; u32 u; } a0, a1;
          a0.f = s[ifr][jc * 2 + 0][r];
          a1.f = s[ifr][jc * 2 + 1][r];
          lpart[ifr][r] += a0.f + a1.f;
          sPd[jc * 2048 + (rowb + r) * 16 + lm] = __builtin_amdgcn_perm(a1.u, a0.u, 0x07060302);
        }
    }

    // O += P V   (A = own wave's P rows; B = sigma-permuted Vt — consistent j order)
#pragma unroll
    for (int c = 0; c < 2; c++)
#pragma unroll
      for (int ifr = 0; ifr < 2; ifr++){
        s8v ph = *(const s8v*)&sP[c * 4096 + (wave * 32 + ifr * 16 + lm) * 32 + quad * 8];
#pragma unroll
        for (int fd = 0; fd < 4; fd++){
          s8v vh = *(const s8v*)&sV[c * 2048 + (fd * 16 + lm) * 32 + quad * 8];
          oacc[ifr][fd] = MFMA16(ph, vh, oacc[ifr][fd]);
        }
      }
    __syncthreads();   // all waves done reading sK/sV before next staging
  }

  // final l reduction (within each 16-lane group) + normalize + store
#pragma unroll
  for (int ifr = 0; ifr < 2; ifr++){
#pragma unroll
    for (int off = 1; off < 16; off <<= 1)
#pragma unroll
      for (int r = 0; r < 4; r++)
        lpart[ifr][r] += __shfl_xor(lpart[ifr][r], off, 64);
    float inv[4];
#pragma unroll
    for (int r = 0; r < 4; r++) inv[r] = 1.f / lpart[ifr][r];
#pragma unroll
    for (int fd = 0; fd < 4; fd++){
      int dcol = h * DH + fd * 16 + lm;
#pragma unroll
      for (int r = 0; r < 4; r++){
        int tok = tok0 + wave * 32 + ifr * 16 + quad * 4 + r;
        Oh[(size_t)tok * DIMK + dcol] = f2bf(oacc[ifr][fd][r] * inv[r]);
      }
    }
  }
}

extern "C" void kernel_launch(void* const* d_in, const int* in_sizes, int n_in,
                              void* d_out, int out_size, void* d_ws, size_t ws_size,
                              hipStream_t stream) {
  const float* x   = (const float*)d_in[0];
  const float* Wq  = (const float*)d_in[1];
  const float* Wkv = (const float*)d_in[2];
  const float* Wo  = (const float*)d_in[3];
  const float* bo  = (const float*)d_in[4];
  float* out = (float*)d_out;

  char* ws = (char*)d_ws;
  size_t off = 0;
  auto alloc = [&](size_t bytes) -> u16* {
    u16* p = (u16*)(ws + off);
    off += (bytes + 255) & ~(size_t)255;
    return p;
  };
  const size_t TK2 = (size_t)TOKENS * DIMK * 2;   // 16.78 MB per bf16 plane
  u16* xh  = alloc(TK2);
  u16* Wh  = alloc((size_t)3072 * DIMK * 2);      // [Wq|Wkv]^T  [3072][1024]
  u16* WOh = alloc((size_t)1024 * DIMK * 2);      // Wo^T        [1024][1024]
  u16* Qh  = alloc(TK2);
  u16* Kh  = alloc(TK2);
  u16* Vth = alloc(TK2);
  u16* Oh  = alloc(TK2);

  // 1) cast x to bf16
  k_cast<<<dim3((TOKENS * DIMK) / 1024), 256, 0, stream>>>(x, xh);
  // 2) transpose weights to n-major
  k_transpose<<<dim3(48, 16), 256, 0, stream>>>(Wq, 1024, Wkv, 2048, DIMK, Wh);
  k_transpose<<<dim3(16, 16), 256, 0, stream>>>(Wo, 1024, Wo, 1024, DIMK, WOh);
  // 3) QKV projection (N=3072): 256x128 tile, m-partition L2-residency swizzle
  k_gemm_qkv<<<dim3(24 * 32), 256, 0, stream>>>(xh, Wh, Qh, Kh, Vth);
  // 4) flash attention (max-free softmax), XCD (b,h)-grouping
  k_attn<<<dim3(16 * NH * 4), 256, 0, stream>>>(Qh, Kh, Vth, Oh);
  // 5) output projection + bias: m-partition L2-residency swizzle
  k_gemm_op<<<dim3(8 * 64), 256, 0, stream>>>(Oh, WOh, bo, out);
}